// Round 1
// 299.265 us; speedup vs baseline: 1.1251x; 1.1251x over previous
//
#include <hip/hip_runtime.h>

// RAVNet ragged attention, bf16 MFMA version, v2 (occupancy push).
// B=4096 groups, C=81, DK=64, N<=128. One 256-thread block (4 waves) per group.
// v2 changes vs v1 (336.9us):
//  - Phase 0 (x -> LDS staging) removed: phase 1 is row-split (wave w owns row
//    tiles {w, w+4}) and loads x fragments straight from global (L2/L3-hot),
//    each row read exactly once per block.
//  - Q never goes to persistent LDS: the owning wave keeps its Q tiles in
//    registers (C-layout) and transposes via the wave-private P scratch.
//  - O staging overlays the P scratch (ap fragments are register-resident
//    before O writes; threadfence-block guards the LDS RAW/WAR hazards).
//  LDS: 80,896 B -> 53,248 B  => 2 -> 3 blocks/CU (12 waves/CU).

typedef __attribute__((ext_vector_type(8))) short short8;   // 8 bf16 = 4 VGPRs
typedef __attribute__((ext_vector_type(4))) float f32x4;
typedef __attribute__((ext_vector_type(4))) short short4v;

constexpr int C  = 81;
constexpr int DK = 64;
constexpr int CP = 96;     // C padded to 3*32 for K-dim of projections

// ---- LDS layout (ushort units) ----
constexpr int QK_STRIDE = 72;   // K rows      (36 dwords: 4r%32 -> 2-way)
constexpr int VT_STRIDE = 136;  // v^T rows    (68 dwords: 4r%32 -> 2-way)
constexpr int P_STRIDE  = 136;  // per-wave P scratch
constexpr int QS_STRIDE = 72;   // Q-transpose scratch (inside P region)
constexpr int O_STRIDE  = 72;   // O scratch (inside P region)
constexpr int OFF_K  = 0;                              // 128 rows
constexpr int OFF_VT = OFF_K + 128 * QK_STRIDE;        // 9216
constexpr int OFF_P  = OFF_VT + 64 * VT_STRIDE;        // 17920, + wave*16*P_STRIDE
constexpr int SMEM_TOT = OFF_P + 4 * 16 * P_STRIDE;    // 26624 ushorts = 53,248 B

__device__ inline ushort f2b(float f) {   // fp32 -> bf16 bits, RNE
    uint u = __float_as_uint(f);
    uint r = (u + 0x7fffu + ((u >> 16) & 1u)) >> 16;
    return (ushort)r;
}

#define MFMA16(a, b, c) __builtin_amdgcn_mfma_f32_16x16x32_bf16((a), (b), (c), 0, 0, 0)

// ---------------- Kernel 1: exclusive scan of counts -> offsets ----------------
__global__ void scan_counts(const int* __restrict__ counts,
                            int* __restrict__ offsets, int n) {
    __shared__ int part[256];
    int tid = threadIdx.x;
    int per = (n + 255) >> 8;
    int base = tid * per;
    int s = 0;
    for (int i = 0; i < per; i++) {
        int idx = base + i;
        if (idx < n) s += counts[idx];
    }
    part[tid] = s;
    __syncthreads();
    for (int off = 1; off < 256; off <<= 1) {
        int v = (tid >= off) ? part[tid - off] : 0;
        __syncthreads();
        part[tid] += v;
        __syncthreads();
    }
    int run = (tid == 0) ? 0 : part[tid - 1];
    for (int i = 0; i < per; i++) {
        int idx = base + i;
        if (idx < n) { offsets[idx] = run; run += counts[idx]; }
    }
}

// ------- Kernel 2: weights -> bf16, transposed for contiguous B-fragments -------
// wqT/wkT/wvT: [64][96]  wT[n][k] = W[k][n] (k<81, else 0); wvT folds prior@wv.
// wuT: [96][64] wuT[n][k] = wu[k][n] (n<81, else 0).
__global__ void prep_weights(const float* __restrict__ prior,
                             const float* __restrict__ wq, const float* __restrict__ wk,
                             const float* __restrict__ wv, const float* __restrict__ wu,
                             ushort* __restrict__ wqT, ushort* __restrict__ wkT,
                             ushort* __restrict__ wvT, ushort* __restrict__ wuT) {
    int idx = blockIdx.x * 256 + threadIdx.x;
    int sec = idx / (DK * CP);
    int i   = idx - sec * (DK * CP);
    if (sec == 0 || sec == 1) {
        int n = i / CP, k = i - (i / CP) * CP;
        const float* w = (sec == 0) ? wq : wk;
        ushort* dst    = (sec == 0) ? wqT : wkT;
        dst[n * CP + k] = (k < C) ? f2b(w[k * DK + n]) : (ushort)0;
    } else if (sec == 2) {
        int n = i / CP, k = i - (i / CP) * CP;
        float s = 0.f;
        if (k < C)
            for (int e = 0; e < C; e++) s = fmaf(prior[k * C + e], wv[e * DK + n], s);
        wvT[n * CP + k] = (k < C) ? f2b(s) : (ushort)0;
    } else {
        int n = i / DK, k = i - (i / DK) * DK;   // n < 96, k < 64
        wuT[n * DK + k] = (n < C) ? f2b(wu[k * C + n]) : (ushort)0;
    }
}

// ---------------- Kernel 3: per-group MFMA attention ----------------
__launch_bounds__(256, 3)
__global__ void ravnet_mfma(const float* __restrict__ x,
                            const int* __restrict__ counts,
                            const int* __restrict__ offsets,
                            const ushort* __restrict__ wqT, const ushort* __restrict__ wkT,
                            const ushort* __restrict__ wvT, const ushort* __restrict__ wuT,
                            const float* __restrict__ bq, const float* __restrict__ bk,
                            const float* __restrict__ bv, const float* __restrict__ bu,
                            float* __restrict__ out) {
    __shared__ __align__(16) ushort sm[SMEM_TOT];   // 53,248 B -> 3 blocks/CU

    const int b    = blockIdx.x;
    const int N    = counts[b];
    const long off = offsets[b];
    const int tid  = threadIdx.x;
    const int lane = tid & 63;
    const int wave = tid >> 6;
    const int quad = lane >> 4;      // 0..3
    const int m16  = lane & 15;      // 0..15
    const int NT8  = (N + 15) >> 4;  // 16-row tiles, <=8
    const int NT4  = (N + 31) >> 5;  // 32-col K-steps for P@V, <=4
    const float* xsrc = x + off * C;

    // Q tiles owned by this wave, C-layout: qreg[t][nt][r] = Q[qt*16+quad*4+r][nt*16+m16]
    short4v qreg[2][4];

    // ---- Phase 1 (row-split): wave w computes Q/K/V for row tiles {w, w+4}.
    // x fragments straight from global (once per row), Q stays in registers,
    // K -> LDS row-major, V -> LDS transposed. ----
    #pragma unroll
    for (int t = 0; t < 2; t++) {
        const int rt = wave + 4 * t;
        if (rt < NT8) {
            const int row  = rt * 16 + m16;
            const bool vrow = row < N;
            const float* xr = xsrc + (long)(vrow ? row : (N - 1)) * C;  // clamped: no OOB
            short8 ax[3];
            #pragma unroll
            for (int ks = 0; ks < 2; ks++) {          // cols < 64 < C: no col guard
                const int c0 = ks * 32 + quad * 8;
                short8 a;
                #pragma unroll
                for (int e = 0; e < 8; e++) a[e] = (short)f2b(vrow ? xr[c0 + e] : 0.f);
                ax[ks] = a;
            }
            {                                          // ks=2: cols 64..95, guard c<81
                const int c0 = 64 + quad * 8;
                short8 a;
                #pragma unroll
                for (int e = 0; e < 8; e++) {
                    const int c = c0 + e;
                    a[e] = (short)((vrow && c < C) ? f2b(xr[c]) : (ushort)0);
                }
                ax[2] = a;
            }
            // Q -> registers (C-layout, bf16)
            #pragma unroll
            for (int nt = 0; nt < 4; nt++) {
                const int n = nt * 16 + m16;
                f32x4 acc = {0.f, 0.f, 0.f, 0.f};
                #pragma unroll
                for (int ks = 0; ks < 3; ks++)
                    acc = MFMA16(ax[ks], *(const short8*)(wqT + n * CP + ks * 32 + quad * 8), acc);
                const float bb = bq[n];
                short4v pk;
                #pragma unroll
                for (int r = 0; r < 4; r++) pk[r] = (short)f2b(acc[r] + bb);
                qreg[t][nt] = pk;
            }
            // K -> LDS row-major
            #pragma unroll
            for (int nt = 0; nt < 4; nt++) {
                const int n = nt * 16 + m16;
                f32x4 acc = {0.f, 0.f, 0.f, 0.f};
                #pragma unroll
                for (int ks = 0; ks < 3; ks++)
                    acc = MFMA16(ax[ks], *(const short8*)(wkT + n * CP + ks * 32 + quad * 8), acc);
                const float bb = bk[n];
                #pragma unroll
                for (int r = 0; r < 4; r++)
                    sm[OFF_K + (rt * 16 + quad * 4 + r) * QK_STRIDE + n] = f2b(acc[r] + bb);
            }
            // V -> LDS transposed: VT[dim][inst], 4 contiguous insts -> 8B store
            #pragma unroll
            for (int nt = 0; nt < 4; nt++) {
                const int n = nt * 16 + m16;
                f32x4 acc = {0.f, 0.f, 0.f, 0.f};
                #pragma unroll
                for (int ks = 0; ks < 3; ks++)
                    acc = MFMA16(ax[ks], *(const short8*)(wvT + n * CP + ks * 32 + quad * 8), acc);
                const float bb = bv[n];
                short4v pk;
                #pragma unroll
                for (int r = 0; r < 4; r++) pk[r] = (short)f2b(acc[r] + bb);
                *(short4v*)(sm + OFF_VT + n * VT_STRIDE + rt * 16 + quad * 4) = pk;
            }
        }
    }
    // VT pad cols [NT8*16, NT4*32) must be finite (P=0 there; NaN*0=NaN). Only
    // exists when NT8 is odd: zero exactly 16 cols x 64 dims (1 store/thread).
    if (NT8 & 1) {
        const int R = NT8 * 16;
        const int d = tid >> 2, c4 = (tid & 3) << 2;
        short4v z = {0, 0, 0, 0};
        *(short4v*)(sm + OFF_VT + d * VT_STRIDE + R + c4) = z;
    }
    __syncthreads();

    // ---- Phase 2: attention + output projection. Wave w handles q-tiles {w, w+4}.
    // The wave-private P region serves, in sequence: Q-transpose scratch, P, O. ----
    ushort* Pw = sm + OFF_P + wave * (16 * P_STRIDE);
    #pragma unroll
    for (int t = 0; t < 2; t++) {
        const int qt = wave + 4 * t;
        if (qt < NT8) {
            // (a) Q: C-layout regs -> scratch -> A-fragments
            #pragma unroll
            for (int nt = 0; nt < 4; nt++) {
                const short4v q4 = qreg[t][nt];
                #pragma unroll
                for (int r = 0; r < 4; r++)
                    Pw[(quad * 4 + r) * QS_STRIDE + nt * 16 + m16] = (ushort)q4[r];
            }
            __threadfence_block();
            short8 aq[2];
            #pragma unroll
            for (int ks = 0; ks < 2; ks++)
                aq[ks] = *(const short8*)(Pw + m16 * QS_STRIDE + ks * 32 + quad * 8);
            // (b) S = Q K^T (full row block in registers, C-layout)
            f32x4 sacc[8];
            #pragma unroll
            for (int ct = 0; ct < 8; ct++) {
                if (ct < NT8) {
                    f32x4 a = {0.f, 0.f, 0.f, 0.f};
                    #pragma unroll
                    for (int ks = 0; ks < 2; ks++) {
                        short8 kb = *(const short8*)(sm + OFF_K + (ct * 16 + m16) * QK_STRIDE +
                                                     ks * 32 + quad * 8);
                        a = MFMA16(aq[ks], kb, a);
                    }
                    sacc[ct] = a;
                }
            }
            // scale + key-col mask + row max (rows live in quads; reduce across m16)
            float mr[4] = {-3e38f, -3e38f, -3e38f, -3e38f};
            #pragma unroll
            for (int ct = 0; ct < 8; ct++) if (ct < NT8) {
                const bool valid = (ct * 16 + m16) < N;
                #pragma unroll
                for (int r = 0; r < 4; r++) {
                    float s = valid ? sacc[ct][r] * 0.125f : -3e38f;
                    sacc[ct][r] = s;
                    mr[r] = fmaxf(mr[r], s);
                }
            }
            #pragma unroll
            for (int r = 0; r < 4; r++) {
                mr[r] = fmaxf(mr[r], __shfl_xor(mr[r], 1, 64));
                mr[r] = fmaxf(mr[r], __shfl_xor(mr[r], 2, 64));
                mr[r] = fmaxf(mr[r], __shfl_xor(mr[r], 4, 64));
                mr[r] = fmaxf(mr[r], __shfl_xor(mr[r], 8, 64));
            }
            float lr[4] = {0.f, 0.f, 0.f, 0.f};
            #pragma unroll
            for (int ct = 0; ct < 8; ct++) if (ct < NT8) {
                #pragma unroll
                for (int r = 0; r < 4; r++) {
                    float p = __expf(sacc[ct][r] - mr[r]);
                    sacc[ct][r] = p;
                    lr[r] += p;
                }
            }
            #pragma unroll
            for (int r = 0; r < 4; r++) {
                lr[r] += __shfl_xor(lr[r], 1, 64);
                lr[r] += __shfl_xor(lr[r], 2, 64);
                lr[r] += __shfl_xor(lr[r], 4, 64);
                lr[r] += __shfl_xor(lr[r], 8, 64);
            }
            // (c) P -> LDS (C-layout scatter), then re-read as A-fragments
            #pragma unroll
            for (int ct = 0; ct < 8; ct++) if (ct < NT8) {
                #pragma unroll
                for (int r = 0; r < 4; r++)
                    Pw[(quad * 4 + r) * P_STRIDE + ct * 16 + m16] = f2b(sacc[ct][r]);
            }
            if (NT8 & 1) {   // zero pad cols [NT8*16, NT4*32)
                #pragma unroll
                for (int r = 0; r < 4; r++)
                    Pw[(quad * 4 + r) * P_STRIDE + NT8 * 16 + m16] = 0;
            }
            __threadfence_block();
            short8 ap[4];
            #pragma unroll
            for (int kt = 0; kt < 4; kt++) if (kt < NT4)
                ap[kt] = *(const short8*)(Pw + m16 * P_STRIDE + kt * 32 + quad * 8);
            __threadfence_block();   // ap reads complete before O overwrites P region
            // (d) O = P V (B from VT), normalize by row sum, stage bf16 O over P
            float linv[4];
            #pragma unroll
            for (int r = 0; r < 4; r++) linv[r] = (lr[r] > 0.f) ? 1.f / lr[r] : 0.f;
            #pragma unroll
            for (int ot = 0; ot < 4; ot++) {
                f32x4 oa = {0.f, 0.f, 0.f, 0.f};
                #pragma unroll
                for (int kt = 0; kt < 4; kt++) if (kt < NT4) {
                    short8 vb = *(const short8*)(sm + OFF_VT + (ot * 16 + m16) * VT_STRIDE +
                                                 kt * 32 + quad * 8);
                    oa = MFMA16(ap[kt], vb, oa);
                }
                #pragma unroll
                for (int r = 0; r < 4; r++)
                    Pw[(quad * 4 + r) * O_STRIDE + ot * 16 + m16] = f2b(oa[r] * linv[r]);
            }
            __threadfence_block();
            short8 ao[2];
            #pragma unroll
            for (int ks = 0; ks < 2; ks++)
                ao[ks] = *(const short8*)(Pw + m16 * O_STRIDE + ks * 32 + quad * 8);
            __threadfence_block();   // ao reads complete before next iter's Q-scratch writes
            // out = O @ Wu + bu, masked scatter to ragged flat layout
            #pragma unroll
            for (int ct = 0; ct < 6; ct++) {
                f32x4 acc = {0.f, 0.f, 0.f, 0.f};
                #pragma unroll
                for (int ks = 0; ks < 2; ks++) {
                    short8 wb = *(const short8*)(wuT + (ct * 16 + m16) * DK + ks * 32 + quad * 8);
                    acc = MFMA16(ao[ks], wb, acc);
                }
                const int e = ct * 16 + m16;
                if (e < C) {
                    const float bue = bu[e];
                    #pragma unroll
                    for (int r = 0; r < 4; r++) {
                        const int row = qt * 16 + quad * 4 + r;
                        if (row < N) out[(off + row) * C + e] = acc[r] + bue;
                    }
                }
            }
        }
    }
}

// ---------------- launch ----------------
extern "C" void kernel_launch(void* const* d_in, const int* in_sizes, int n_in,
                              void* d_out, int out_size, void* d_ws, size_t ws_size,
                              hipStream_t stream) {
    const float* x      = (const float*)d_in[0];
    const int*   counts = (const int*)  d_in[1];
    const float* prior  = (const float*)d_in[2];
    const float* wq     = (const float*)d_in[3];
    const float* bq     = (const float*)d_in[4];
    const float* wk     = (const float*)d_in[5];
    const float* bk     = (const float*)d_in[6];
    const float* wv     = (const float*)d_in[7];
    const float* bv     = (const float*)d_in[8];
    const float* wu     = (const float*)d_in[9];
    const float* bu     = (const float*)d_in[10];
    float* out = (float*)d_out;

    const int B = in_sizes[1];   // 4096 groups

    // ws: offsets[B] | wqT | wkT | wvT | wuT  (bf16, transposed, padded)
    int*    offsets = (int*)d_ws;
    ushort* wqT = (ushort*)((char*)d_ws + (((size_t)B * sizeof(int) + 255) & ~(size_t)255));
    ushort* wkT = wqT + DK * CP;
    ushort* wvT = wkT + DK * CP;
    ushort* wuT = wvT + DK * CP;

    scan_counts<<<1, 256, 0, stream>>>(counts, offsets, B);
    prep_weights<<<(4 * DK * CP + 255) / 256, 256, 0, stream>>>(
        prior, wq, wk, wv, wu, wqT, wkT, wvT, wuT);
    ravnet_mfma<<<B, 256, 0, stream>>>(x, counts, offsets,
                                       wqT, wkT, wvT, wuT,
                                       bq, bk, bv, bu, out);
}

// Round 2
// 284.488 us; speedup vs baseline: 1.1836x; 1.0519x over previous
//
#include <hip/hip_runtime.h>

// RAVNet ragged attention, bf16 MFMA version, v3 (LDS-free phase 2).
// B=4096 groups, C=81, DK=64, N<=128. One 256-thread block (4 waves) per group.
// v3 changes vs v2 (299us e2e / 165us kernel):
//  - All matmuls computed in TRANSPOSED form (swap MFMA operands) so every
//    intermediate (Q^T, S^T=KQ^T, O^T=V^T P^T, out^T=WuT O^T) lands in a
//    C-layout whose conversion to the next MFMA's B-fragment is a QUAD-LOCAL
//    lane permutation: 8 ds_bpermute (__shfl) + 4 selects per fragment.
//    No P/Q/O LDS scratch, no threadfences, shorter serial chain.
//  - Softmax row now lives across (ct,quad,r) with the query on m16: row
//    max/sum reduce is 2 shfl_xor (16,32) instead of 4; mask & 1/l are
//    per-lane scalars.
//  - LDS: 53,248 B -> 35,840 B (K + VT only)  => 4 blocks/CU, 16 waves/CU.

typedef __attribute__((ext_vector_type(8))) short short8;   // 8 bf16 = 4 VGPRs
typedef __attribute__((ext_vector_type(4))) float f32x4;
typedef __attribute__((ext_vector_type(4))) short short4v;

constexpr int C  = 81;
constexpr int DK = 64;
constexpr int CP = 96;     // C padded to 3*32 for K-dim of projections

// ---- LDS layout (ushort units) ----
constexpr int QK_STRIDE = 72;   // K rows   (36 dwords: 4r%32 -> ~2-way)
constexpr int VT_STRIDE = 136;  // v^T rows (68 dwords: 4r%32 -> ~2-way)
constexpr int OFF_K  = 0;                              // 128 rows x 72
constexpr int OFF_VT = 128 * QK_STRIDE;                // 9216
constexpr int SMEM_TOT = OFF_VT + 64 * VT_STRIDE;      // 17920 ushorts = 35,840 B

__device__ inline ushort f2b(float f) {   // fp32 -> bf16 bits, RNE
    uint u = __float_as_uint(f);
    uint r = (u + 0x7fffu + ((u >> 16) & 1u)) >> 16;
    return (ushort)r;
}
__device__ inline uint pack2bf(float a, float b) {
    return (uint)f2b(a) | ((uint)f2b(b) << 16);
}
__device__ inline uint shflu(uint v, int srcLane) {
    return (uint)__shfl((int)v, srcLane, 64);
}
union U8 { short8 s; uint u[4]; };

#define MFMA16(a, b, c) __builtin_amdgcn_mfma_f32_16x16x32_bf16((a), (b), (c), 0, 0, 0)

// ---------------- Kernel 1: exclusive scan of counts -> offsets ----------------
__global__ void scan_counts(const int* __restrict__ counts,
                            int* __restrict__ offsets, int n) {
    __shared__ int part[256];
    int tid = threadIdx.x;
    int per = (n + 255) >> 8;
    int base = tid * per;
    int s = 0;
    for (int i = 0; i < per; i++) {
        int idx = base + i;
        if (idx < n) s += counts[idx];
    }
    part[tid] = s;
    __syncthreads();
    for (int off = 1; off < 256; off <<= 1) {
        int v = (tid >= off) ? part[tid - off] : 0;
        __syncthreads();
        part[tid] += v;
        __syncthreads();
    }
    int run = (tid == 0) ? 0 : part[tid - 1];
    for (int i = 0; i < per; i++) {
        int idx = base + i;
        if (idx < n) { offsets[idx] = run; run += counts[idx]; }
    }
}

// ------- Kernel 2: weights -> bf16, transposed for contiguous fragments -------
// wqT/wkT/wvT: [64][96]  wT[n][k] = W[k][n] (k<81, else 0); wvT folds prior@wv.
// wuT: [96][64] wuT[n][k] = wu[k][n] (n<81, else 0).
__global__ void prep_weights(const float* __restrict__ prior,
                             const float* __restrict__ wq, const float* __restrict__ wk,
                             const float* __restrict__ wv, const float* __restrict__ wu,
                             ushort* __restrict__ wqT, ushort* __restrict__ wkT,
                             ushort* __restrict__ wvT, ushort* __restrict__ wuT) {
    int idx = blockIdx.x * 256 + threadIdx.x;
    int sec = idx / (DK * CP);
    int i   = idx - sec * (DK * CP);
    if (sec == 0 || sec == 1) {
        int n = i / CP, k = i - (i / CP) * CP;
        const float* w = (sec == 0) ? wq : wk;
        ushort* dst    = (sec == 0) ? wqT : wkT;
        dst[n * CP + k] = (k < C) ? f2b(w[k * DK + n]) : (ushort)0;
    } else if (sec == 2) {
        int n = i / CP, k = i - (i / CP) * CP;
        float s = 0.f;
        if (k < C)
            for (int e = 0; e < C; e++) s = fmaf(prior[k * C + e], wv[e * DK + n], s);
        wvT[n * CP + k] = (k < C) ? f2b(s) : (ushort)0;
    } else {
        int n = i / DK, k = i - (i / DK) * DK;   // n < 96, k < 64
        wuT[n * DK + k] = (n < C) ? f2b(wu[k * C + n]) : (ushort)0;
    }
}

// ---------------- Kernel 3: per-group MFMA attention ----------------
__launch_bounds__(256, 4)
__global__ void ravnet_mfma(const float* __restrict__ x,
                            const int* __restrict__ counts,
                            const int* __restrict__ offsets,
                            const ushort* __restrict__ wqT, const ushort* __restrict__ wkT,
                            const ushort* __restrict__ wvT, const ushort* __restrict__ wuT,
                            const float* __restrict__ bq, const float* __restrict__ bk,
                            const float* __restrict__ bv, const float* __restrict__ bu,
                            float* __restrict__ out) {
    __shared__ __align__(16) ushort sm[SMEM_TOT];   // 35,840 B -> 4 blocks/CU

    const int b    = blockIdx.x;
    const int N    = counts[b];
    const long off = offsets[b];
    const int tid  = threadIdx.x;
    const int lane = tid & 63;
    const int wave = tid >> 6;
    const int quad = lane >> 4;      // 0..3
    const int m16  = lane & 15;      // 0..15
    const int NT8  = (N + 15) >> 4;  // 16-row tiles, <=8
    const int NT4  = (N + 31) >> 5;  // 32-col K-steps for P@V, <=4
    const float* xsrc = x + off * C;

    // quad-shuffle constants: C-layout (lane holds M[m16][tile*16+quad*4+r])
    // -> row-major fragment (lane holds M[m16][kstep*32+quad*8+e]).
    // dwords 0,1 come from src quad (quad&1)*2; dwords 2,3 from that +1;
    // tile index = 2*kstep + (quad>>1).
    const int srcE = ((quad & 1) << 5) + m16;   // ((quad&1)*2)*16 + m16
    const int srcO = srcE + 16;
    const bool hi  = (quad >> 1) != 0;

    // Q fragments for this wave's q-tiles {wave, wave+4}, row-major B-frag layout
    short8 aq[2][2];

    // ---- Phase 1 (row-split): wave w computes Q/K/V for row tiles {w, w+4}.
    // Q^T / K^T via mfma(w*T_frag, x_frag); V via mfma(x_frag, wvT_frag). ----
    #pragma unroll
    for (int t = 0; t < 2; t++) {
        const int rt = wave + 4 * t;
        if (rt < NT8) {
            const int row  = rt * 16 + m16;
            const bool vrow = row < N;
            const float* xr = xsrc + (long)(vrow ? row : (N - 1)) * C;  // clamped
            short8 ax[3];
            #pragma unroll
            for (int ks = 0; ks < 2; ks++) {          // cols < 64 < C
                const int c0 = ks * 32 + quad * 8;
                short8 a;
                #pragma unroll
                for (int e = 0; e < 8; e++) a[e] = (short)f2b(vrow ? xr[c0 + e] : 0.f);
                ax[ks] = a;
            }
            {                                          // ks=2: cols 64..95
                const int c0 = 64 + quad * 8;
                short8 a;
                #pragma unroll
                for (int e = 0; e < 8; e++) {
                    const int c = c0 + e;
                    a[e] = (short)((vrow && c < C) ? f2b(xr[c]) : (ushort)0);
                }
                ax[2] = a;
            }
            // Q^T: lane gets Q[m16-row][nt*16+quad*4+r]; pack; quad-shuffle -> aq
            uint qpk[4][2];
            #pragma unroll
            for (int nt = 0; nt < 4; nt++) {
                f32x4 acc = {0.f, 0.f, 0.f, 0.f};
                #pragma unroll
                for (int ks = 0; ks < 3; ks++)
                    acc = MFMA16(*(const short8*)(wqT + (nt * 16 + m16) * CP + ks * 32 + quad * 8),
                                 ax[ks], acc);
                const f32x4 b4 = *(const f32x4*)(bq + nt * 16 + quad * 4);
                qpk[nt][0] = pack2bf(acc[0] + b4[0], acc[1] + b4[1]);
                qpk[nt][1] = pack2bf(acc[2] + b4[2], acc[3] + b4[3]);
            }
            #pragma unroll
            for (int ks = 0; ks < 2; ks++) {
                uint a0 = shflu(qpk[2 * ks][0], srcE), b0 = shflu(qpk[2 * ks + 1][0], srcE);
                uint a1 = shflu(qpk[2 * ks][1], srcE), b1 = shflu(qpk[2 * ks + 1][1], srcE);
                uint a2 = shflu(qpk[2 * ks][0], srcO), b2 = shflu(qpk[2 * ks + 1][0], srcO);
                uint a3 = shflu(qpk[2 * ks][1], srcO), b3 = shflu(qpk[2 * ks + 1][1], srcO);
                U8 u;
                u.u[0] = hi ? b0 : a0;  u.u[1] = hi ? b1 : a1;
                u.u[2] = hi ? b2 : a2;  u.u[3] = hi ? b3 : a3;
                aq[t][ks] = u.s;
            }
            // K^T: lane gets K[m16-row][nt*16+quad*4+r] -> 8B contiguous store
            #pragma unroll
            for (int nt = 0; nt < 4; nt++) {
                f32x4 acc = {0.f, 0.f, 0.f, 0.f};
                #pragma unroll
                for (int ks = 0; ks < 3; ks++)
                    acc = MFMA16(*(const short8*)(wkT + (nt * 16 + m16) * CP + ks * 32 + quad * 8),
                                 ax[ks], acc);
                const f32x4 b4 = *(const f32x4*)(bk + nt * 16 + quad * 4);
                short4v pk4;
                #pragma unroll
                for (int r = 0; r < 4; r++) pk4[r] = (short)f2b(acc[r] + b4[r]);
                *(short4v*)(sm + OFF_K + (rt * 16 + m16) * QK_STRIDE + nt * 16 + quad * 4) = pk4;
            }
            // V: lane gets V[rt*16+quad*4+r][nt*16+m16] -> VT 8B contiguous store
            #pragma unroll
            for (int nt = 0; nt < 4; nt++) {
                f32x4 acc = {0.f, 0.f, 0.f, 0.f};
                #pragma unroll
                for (int ks = 0; ks < 3; ks++)
                    acc = MFMA16(ax[ks],
                                 *(const short8*)(wvT + (nt * 16 + m16) * CP + ks * 32 + quad * 8),
                                 acc);
                const float bb = bv[nt * 16 + m16];
                short4v pk4;
                #pragma unroll
                for (int r = 0; r < 4; r++) pk4[r] = (short)f2b(acc[r] + bb);
                *(short4v*)(sm + OFF_VT + (nt * 16 + m16) * VT_STRIDE + rt * 16 + quad * 4) = pk4;
            }
        }
    }
    // VT pad cols [NT8*16, NT4*32) must be finite (P=0 there; NaN*0=NaN). Only
    // exists when NT8 is odd: zero 16 cols x 64 dims (1 store/thread).
    if (NT8 & 1) {
        const int R = NT8 * 16;
        const int d = tid >> 2, c4 = (tid & 3) << 2;
        short4v z = {0, 0, 0, 0};
        *(short4v*)(sm + OFF_VT + d * VT_STRIDE + R + c4) = z;
    }
    __syncthreads();

    // ---- Phase 2: attention + out-proj, fully in registers (LDS reads only) ----
    constexpr float SCALE = 0.18033688011112042f;   // 0.125 * log2(e)
    #pragma unroll
    for (int t = 0; t < 2; t++) {
        const int qt = wave + 4 * t;
        if (qt < NT8) {
            // (a) S^T = K Q^T: lane holds S[m16-query][ct*16+quad*4+r]
            f32x4 sacc[8];
            #pragma unroll
            for (int ct = 0; ct < 8; ct++) {
                if (ct < NT8) {
                    f32x4 a = {0.f, 0.f, 0.f, 0.f};
                    #pragma unroll
                    for (int ks = 0; ks < 2; ks++) {
                        short8 kb = *(const short8*)(sm + OFF_K + (ct * 16 + m16) * QK_STRIDE +
                                                     ks * 32 + quad * 8);
                        a = MFMA16(kb, aq[t][ks], a);
                    }
                    sacc[ct] = a;
                }
            }
            // (b) softmax over keys: local (ct,r) then quads (2 shfl_xor)
            float mr = -3e38f;
            #pragma unroll
            for (int ct = 0; ct < 8; ct++) if (ct < NT8) {
                #pragma unroll
                for (int r = 0; r < 4; r++) {
                    const bool valid = (ct * 16 + quad * 4 + r) < N;
                    float s = valid ? sacc[ct][r] * SCALE : -3e38f;
                    sacc[ct][r] = s;
                    mr = fmaxf(mr, s);
                }
            }
            mr = fmaxf(mr, __shfl_xor(mr, 16, 64));
            mr = fmaxf(mr, __shfl_xor(mr, 32, 64));
            float lr = 0.f;
            #pragma unroll
            for (int ct = 0; ct < 8; ct++) if (ct < NT8) {
                #pragma unroll
                for (int r = 0; r < 4; r++) {
                    float p = __builtin_exp2f(sacc[ct][r] - mr);
                    sacc[ct][r] = p;
                    lr += p;
                }
            }
            lr += __shfl_xor(lr, 16, 64);
            lr += __shfl_xor(lr, 32, 64);
            const float linv = 1.f / lr;   // lr >= 1 (max valid key has p=1)
            // (c) P pack + quad-shuffle -> PV B-fragments (pad tiles = 0)
            uint pk[8][2];
            #pragma unroll
            for (int ct = 0; ct < 8; ct++) {
                if (ct < NT8) {
                    pk[ct][0] = pack2bf(sacc[ct][0], sacc[ct][1]);
                    pk[ct][1] = pack2bf(sacc[ct][2], sacc[ct][3]);
                } else {
                    pk[ct][0] = 0u; pk[ct][1] = 0u;
                }
            }
            short8 ap[4];
            #pragma unroll
            for (int kt = 0; kt < 4; kt++) {
                if (kt < NT4) {
                    uint a0 = shflu(pk[2 * kt][0], srcE), b0 = shflu(pk[2 * kt + 1][0], srcE);
                    uint a1 = shflu(pk[2 * kt][1], srcE), b1 = shflu(pk[2 * kt + 1][1], srcE);
                    uint a2 = shflu(pk[2 * kt][0], srcO), b2 = shflu(pk[2 * kt + 1][0], srcO);
                    uint a3 = shflu(pk[2 * kt][1], srcO), b3 = shflu(pk[2 * kt + 1][1], srcO);
                    U8 u;
                    u.u[0] = hi ? b0 : a0;  u.u[1] = hi ? b1 : a1;
                    u.u[2] = hi ? b2 : a2;  u.u[3] = hi ? b3 : a3;
                    ap[kt] = u.s;
                }
            }
            // (d) O^T = V^T P^T: lane holds O[m16-query][ot*16+quad*4+r]
            uint opk[4][2];
            #pragma unroll
            for (int ot = 0; ot < 4; ot++) {
                f32x4 oa = {0.f, 0.f, 0.f, 0.f};
                #pragma unroll
                for (int kt = 0; kt < 4; kt++) if (kt < NT4) {
                    short8 vb = *(const short8*)(sm + OFF_VT + (ot * 16 + m16) * VT_STRIDE +
                                                 kt * 32 + quad * 8);
                    oa = MFMA16(vb, ap[kt], oa);
                }
                opk[ot][0] = pack2bf(oa[0] * linv, oa[1] * linv);
                opk[ot][1] = pack2bf(oa[2] * linv, oa[3] * linv);
            }
            // (e) quad-shuffle O^T -> out-proj B-fragments
            short8 ao[2];
            #pragma unroll
            for (int ks = 0; ks < 2; ks++) {
                uint a0 = shflu(opk[2 * ks][0], srcE), b0 = shflu(opk[2 * ks + 1][0], srcE);
                uint a1 = shflu(opk[2 * ks][1], srcE), b1 = shflu(opk[2 * ks + 1][1], srcE);
                uint a2 = shflu(opk[2 * ks][0], srcO), b2 = shflu(opk[2 * ks + 1][0], srcO);
                uint a3 = shflu(opk[2 * ks][1], srcO), b3 = shflu(opk[2 * ks + 1][1], srcO);
                U8 u;
                u.u[0] = hi ? b0 : a0;  u.u[1] = hi ? b1 : a1;
                u.u[2] = hi ? b2 : a2;  u.u[3] = hi ? b3 : a3;
                ao[ks] = u.s;
            }
            // (f) out^T = WuT O^T: lane holds out[m16-query][ct*16+quad*4+r]
            const int row = qt * 16 + m16;
            #pragma unroll
            for (int ct = 0; ct < 6; ct++) {
                f32x4 acc = {0.f, 0.f, 0.f, 0.f};
                #pragma unroll
                for (int ks = 0; ks < 2; ks++) {
                    short8 wb = *(const short8*)(wuT + (ct * 16 + m16) * DK + ks * 32 + quad * 8);
                    acc = MFMA16(wb, ao[ks], acc);
                }
                if (row < N) {
                    #pragma unroll
                    for (int r = 0; r < 4; r++) {
                        const int e = ct * 16 + quad * 4 + r;
                        if (e < C) out[(off + row) * C + e] = acc[r] + bu[e];
                    }
                }
            }
        }
    }
}

// ---------------- launch ----------------
extern "C" void kernel_launch(void* const* d_in, const int* in_sizes, int n_in,
                              void* d_out, int out_size, void* d_ws, size_t ws_size,
                              hipStream_t stream) {
    const float* x      = (const float*)d_in[0];
    const int*   counts = (const int*)  d_in[1];
    const float* prior  = (const float*)d_in[2];
    const float* wq     = (const float*)d_in[3];
    const float* bq     = (const float*)d_in[4];
    const float* wk     = (const float*)d_in[5];
    const float* bk     = (const float*)d_in[6];
    const float* wv     = (const float*)d_in[7];
    const float* bv     = (const float*)d_in[8];
    const float* wu     = (const float*)d_in[9];
    const float* bu     = (const float*)d_in[10];
    float* out = (float*)d_out;

    const int B = in_sizes[1];   // 4096 groups

    // ws: offsets[B] | wqT | wkT | wvT | wuT  (bf16, transposed, padded)
    int*    offsets = (int*)d_ws;
    ushort* wqT = (ushort*)((char*)d_ws + (((size_t)B * sizeof(int) + 255) & ~(size_t)255));
    ushort* wkT = wqT + DK * CP;
    ushort* wvT = wkT + DK * CP;
    ushort* wuT = wvT + DK * CP;

    scan_counts<<<1, 256, 0, stream>>>(counts, offsets, B);
    prep_weights<<<(4 * DK * CP + 255) / 256, 256, 0, stream>>>(
        prior, wq, wk, wv, wu, wqT, wkT, wvT, wuT);
    ravnet_mfma<<<B, 256, 0, stream>>>(x, counts, offsets,
                                       wqT, wkT, wvT, wuT,
                                       bq, bk, bv, bu, out);
}